// Round 7
// baseline (640.068 us; speedup 1.0000x reference)
//
#include <hip/hip_runtime.h>
#include <hip/hip_bf16.h>

#define HH 192
#define WW 192
#define HW (HH*WW)

typedef unsigned short u16;
typedef __attribute__((ext_vector_type(8))) short short8;
typedef __attribute__((ext_vector_type(16))) float float16;
typedef __attribute__((ext_vector_type(4))) float f32x4;

__device__ __forceinline__ float b2f(u16 u){
  union { unsigned int i; float f; } v; v.i = ((unsigned int)u) << 16; return v.f;
}
__device__ __forceinline__ u16 f2b(float f){
  union { unsigned int i; float f; } v; v.f = f;
  unsigned int r = v.i + 0x7FFFu + ((v.i >> 16) & 1u);
  return (u16)(r >> 16);
}
__device__ __forceinline__ void up2(unsigned int w, float& lo, float& hi){
  union { unsigned int i; float f; } a, b;
  a.i = w << 16; b.i = w & 0xFFFF0000u;
  lo = a.f; hi = b.f;
}
__device__ __forceinline__ float lrelu(float x){ return x >= 0.f ? x : 0.1f*x; }
__device__ __forceinline__ float ldmix(const void* p, int i, bool bf){
  return bf ? b2f(((const u16*)p)[i]) : ((const float*)p)[i];
}

using bf2 = __attribute__((ext_vector_type(2))) __bf16;
__device__ __forceinline__ float dot2bf(unsigned int a, unsigned int b, float c){
#if __has_builtin(__builtin_amdgcn_fdot2_f32_bf16)
  union { unsigned int u; bf2 v; } ua, ub; ua.u = a; ub.u = b;
  return __builtin_amdgcn_fdot2_f32_bf16(ua.v, ub.v, c, false);
#else
  float al,ah,bl,bh; up2(a,al,ah); up2(b,bl,bh);
  return c + al*bl + ah*bh;
#endif
}

union AU { uint4 q; short8 s; };
__device__ __forceinline__ short8 s8(const uint4& q){ AU u; u.q = q; return u.s; }

__global__ __launch_bounds__(256) void detect_k(const unsigned int* __restrict__ w, int* __restrict__ flag){
  __shared__ int cnt;
  if (threadIdx.x == 0) cnt = 0;
  __syncthreads();
  unsigned int v = w[(size_t)threadIdx.x * 1024];
  int e = (v >> 7) & 0xFF;
  bool ok = ((v & 0xFFFFu) == 0u) || (e > 100 && e < 150);
  if (ok) atomicAdd(&cnt, 1);
  __syncthreads();
  if (threadIdx.x == 0) *flag = (cnt >= 192) ? 1 : 0;
}

// NCHW (fp32 or bf16) -> NHWC bf16 [8][HW][64] via LDS transpose tile.
__global__ __launch_bounds__(256) void cvt_t(const void* __restrict__ pred, const void* __restrict__ refp,
                                             u16* __restrict__ X1, const int* __restrict__ flag){
  __shared__ u16 t[64*72];
  int tid = threadIdx.x;
  int px0 = blockIdx.x*64, img = blockIdx.y;
  bool bf = (*flag != 0);
  const void* src = (img < 4) ? pred : refp;
  int im = (img < 4) ? img : img - 4;
  for (int e = tid; e < 4096; e += 256){
    int ch = e >> 6, px = e & 63;
    t[px*72 + ch] = f2b(ldmix(src, (im*64 + ch)*HW + px0 + px, bf));
  }
  __syncthreads();
  int px = tid >> 2, q = tid & 3;
  uint4 v0 = *(const uint4*)(t + px*72 + q*16);
  uint4 v1 = *(const uint4*)(t + px*72 + q*16 + 8);
  u16* dst = X1 + ((size_t)img*HW + px0 + px)*64 + q*16;
  *(uint4*)dst = v0;
  *(uint4*)(dst + 8) = v1;
}

// Weight prep.
__global__ __launch_bounds__(256) void prep_w(const void* __restrict__ w1, const void* __restrict__ w2,
                                              const void* __restrict__ wr, const void* __restrict__ wp,
                                              const void* __restrict__ b1, const void* __restrict__ b2,
                                              const void* __restrict__ rb,
                                              u16* __restrict__ w1m, u16* __restrict__ w2m,
                                              float* __restrict__ wrf, unsigned int* __restrict__ wpb,
                                              float* __restrict__ b1f, float* __restrict__ b2f,
                                              float* __restrict__ rbf, const int* __restrict__ flag){
  int i = blockIdx.x*256 + threadIdx.x;
  bool bf = (*flag != 0);
  if (i < 36864){
    int j = i & 7, lane = (i>>3) & 63, cot = (i>>9) & 1, ks = (i>>10) & 3, tap = i >> 12;
    int co = cot*32 + (lane & 31), ci = ks*16 + (lane>>5)*8 + j;
    w1m[i] = f2b(ldmix(w1, (co*64 + ci)*9 + tap, bf));
  }
  if (i < 73728){
    int j = i & 7, lane = (i>>3) & 63, cot = (i>>9) & 3, ks = (i>>11) & 3, tap = i >> 13;
    int co = cot*32 + (lane & 31), ci = ks*16 + (lane>>5)*8 + j;
    w2m[i] = f2b(ldmix(w2, (co*64 + ci)*9 + tap, bf));
  }
  if (i < 4096){ int co = i & 31; int ci = i >> 5;
    wrf[ci*32+co] = ldmix(wr, co*128+ci, bf); }
  if (i < 4266){
    int cp = i/18; int rr = i - cp*18; int tap = rr >> 1; int o = rr & 1;
    int c0 = 2*cp, c1 = c0 + 1;
    float f0 = ldmix(wp, (o*473+c0)*9+tap, bf);
    float f1 = (c1 < 473) ? ldmix(wp, (o*473+c1)*9+tap, bf) : 0.f;
    wpb[i] = (unsigned int)f2b(f0) | ((unsigned int)f2b(f1) << 16);
  }
  if (i < 64)  b1f[i] = ldmix(b1, i, bf);
  if (i < 128) b2f[i] = ldmix(b2, i, bf);
  if (i < 32)  rbf[i] = ldmix(rb, i, bf);
}

// MFMA implicit-GEMM 3x3 conv, pad=1, NHWC bf16 in/out, bias+lrelu.
template<int WCO>
__global__ __launch_bounds__(WCO*128) void conv_mfma(const u16* __restrict__ in, const u16* __restrict__ wm,
                                                     const float* __restrict__ bias, u16* __restrict__ out){
  constexpr int COUT = WCO*64;
  constexpr int NCOT = WCO*2;
  constexpr int THREADS = WCO*128;
  constexpr int CO_PAD = COUT + 8;
  constexpr int SLAB = 6*34*72;            // 14688 u16
  constexpr int OT   = 128*CO_PAD;
  __shared__ __align__(16) u16 smem[(SLAB > OT) ? SLAB : OT];

  int tid = threadIdx.x, lane = tid & 63, w = tid >> 6;
  int wr = w & 1, wc = w >> 1;
  int n = lane & 31, kh = lane >> 5;
  int x0 = blockIdx.x*32, y0 = blockIdx.y*4, img = blockIdx.z;
  const u16* inb = in + (size_t)img*HW*64;

  float16 acc[2][2];
  #pragma unroll
  for (int t=0;t<2;t++)
    #pragma unroll
    for (int c=0;c<2;c++)
      #pragma unroll
      for (int k=0;k<16;k++) acc[t][c][k] = 0.f;

  for (int e = tid; e < 1632; e += THREADS){
    int c8 = e & 7; int pp = e >> 3;
    int row = pp / 34, pos = pp - row*34;
    int gy = y0 + row - 1, gx = x0 + pos - 1;
    uint4 v = make_uint4(0,0,0,0);
    if (gy >= 0 && gy < HH && gx >= 0 && gx < WW)
      v = *(const uint4*)(inb + ((size_t)gy*WW + gx)*64 + c8*8);
    *(uint4*)(smem + pp*72 + c8*8) = v;
  }
  __syncthreads();

  union BU { uint2 u[2]; short8 s; };

  #pragma unroll 1
  for (int ky = 0; ky < 3; ++ky){
    #pragma unroll 1
    for (int kx = 0; kx < 3; ++kx){
      int tap = ky*3 + kx;
      #pragma unroll
      for (int ks = 0; ks < 4; ++ks){
        AU a0, a1;
        const u16* wmp = wm + (((size_t)(tap*4 + ks)*NCOT + wc*2)*64 + lane)*8;
        a0.q = *(const uint4*)(wmp);
        a1.q = *(const uint4*)(wmp + 512);
        #pragma unroll
        for (int t = 0; t < 2; ++t){
          int row = wr*2 + t + ky;
          int off = (row*34 + n + kx)*72 + ks*16 + kh*8;
          BU b;
          b.u[0] = *(const uint2*)(smem + off);
          b.u[1] = *(const uint2*)(smem + off + 4);
          acc[t][0] = __builtin_amdgcn_mfma_f32_32x32x16_bf16(a0.s, b.s, acc[t][0], 0, 0, 0);
          acc[t][1] = __builtin_amdgcn_mfma_f32_32x32x16_bf16(a1.s, b.s, acc[t][1], 0, 0, 0);
        }
      }
    }
  }

  __syncthreads();
  #pragma unroll
  for (int t = 0; t < 2; ++t){
    int pxl = (wr*2 + t)*32 + n;
    #pragma unroll
    for (int c = 0; c < 2; ++c){
      int cob = wc*64 + c*32 + 4*kh;
      #pragma unroll
      for (int p = 0; p < 8; ++p){
        int co = cob + (p&1)*2 + (p>>1)*8;
        float2 bb = *(const float2*)(bias + co);
        float v0 = lrelu(acc[t][c][2*p]   + bb.x);
        float v1 = lrelu(acc[t][c][2*p+1] + bb.y);
        unsigned int pk = (unsigned int)f2b(v0) | ((unsigned int)f2b(v1) << 16);
        *(unsigned int*)(smem + pxl*CO_PAD + co) = pk;
      }
    }
  }
  __syncthreads();
  int px, part;
  if (WCO == 2){ px = tid >> 1; part = tid & 1; } else { px = tid; part = 0; }
  const u16* sp = smem + px*CO_PAD + part*64;
  u16* gp = out + ((size_t)img*HW + (size_t)(y0 + (px>>5))*WW + x0 + (px&31))*COUT + part*64;
  #pragma unroll
  for (int k = 0; k < 8; ++k)
    *(uint4*)(gp + k*8) = *(const uint4*)(sp + k*8);
}

// 1x1 redir conv (128->32) + bias + lrelu. X NCHW [b][473][HW]; planes 0..31.
__global__ __launch_bounds__(256) void redir_k(const u16* __restrict__ C2, const float* __restrict__ wrf,
                                               const float* __restrict__ rbf, u16* __restrict__ X){
  int p = blockIdx.x*256 + threadIdx.x;
  int b = p / HW; int pix = p - b*HW;
  const u16* ap = C2 + (size_t)p*128;
  float acc[32];
  #pragma unroll
  for (int j=0;j<32;j++) acc[j]=0.f;
  for (int ci=0; ci<128; ci+=4){
    uint2 aw = *(const uint2*)(ap + ci);
    float a0,a1,a2,a3;
    up2(aw.x,a0,a1); up2(aw.y,a2,a3);
    const float* w0 = wrf + ci*32;
    #pragma unroll
    for (int co=0; co<32; co+=4){
      float4 wv0 = *(const float4*)(w0+co);
      float4 wv1 = *(const float4*)(w0+32+co);
      float4 wv2 = *(const float4*)(w0+64+co);
      float4 wv3 = *(const float4*)(w0+96+co);
      acc[co+0] += a0*wv0.x + a1*wv1.x + a2*wv2.x + a3*wv3.x;
      acc[co+1] += a0*wv0.y + a1*wv1.y + a2*wv2.y + a3*wv3.y;
      acc[co+2] += a0*wv0.z + a1*wv1.z + a2*wv2.z + a3*wv3.z;
      acc[co+3] += a0*wv0.w + a1*wv1.w + a2*wv2.w + a3*wv3.w;
    }
  }
  #pragma unroll
  for (int co=0; co<32; ++co){
    X[(size_t)(b*473 + co)*HW + pix] = f2b(lrelu(acc[co] + rbf[co]));
  }
}

// Zero the orphan (y,dy) plane rows (r = y+2dy-20 outside [0,192)).
__global__ __launch_bounds__(256) void zero_k(u16* __restrict__ X){
  int yi = blockIdx.x, b = blockIdx.y;
  int y = (yi < 20) ? yi : 152 + yi;           // y in [0,20) or [172,192)
  int locnt = (yi < 20) ? ((21 - y) >> 1) : 0; // orphan dy = 0..locnt-1
  int hi0 = (213 - y) >> 1;                    // first orphan dy at high end
  int hicnt = (yi < 20) ? 0 : (21 - hi0);
  int ncnt = locnt + hicnt;
  u16* Xb = X + ((size_t)(b*473 + 32))*HW + (size_t)y*WW;
  int total = ncnt*2016;
  for (int e = threadIdx.x; e < total; e += 256){
    int i = e / 2016, rem = e - i*2016;
    int dy = (i < locnt) ? i : (hi0 + i - locnt);
    int d = rem / 96, xw = rem - d*96;
    *(unsigned int*)(Xb + ((size_t)(dy*21 + d))*HW + 2*xw) = 0u;
  }
}

// ---------------------------------------------------------------------------
// Correlation, round 13: same parity-packed banded-GEMM math as round 10,
// restructured for concurrency. Round 10 was stall-bound: 4-wave blocks,
// 2 barriers/dy, occupancy 18% (1.4 blocks/CU effective) -> every barrier +
// store drain exposed (~14K cy/dy vs ~2K of work).
// Now: block = (b, r, u-half) = 1536 blocks x 128 thr (2 waves = 2 parities
// of one 96-px x-range). 6 blocks/CU ALL resident (launch_bounds(128,3) ->
// VGPR cap 170 >= ~164 live state, no RA squeeze). Barriers sync only 2
// waves; 5 other blocks fill stalls. smE row stride 100 u16 (odd dword
// stride) -> conflict-free extract writes and readback.
// XCD swizzle keeps uh pairs + neighbor r on one XCD (B/A rows L2-hot,
// boundary lines merge in L2).
// ---------------------------------------------------------------------------
__global__ __launch_bounds__(128,3) void corr_k(const u16* __restrict__ C2, u16* __restrict__ X){
  __shared__ __align__(16) u16 smE[21*100 + 4];

  int bid = blockIdx.x;
  int v = (bid & 7)*192 + (bid >> 3);    // XCD-contiguous, bijective (1536 = 8*192)
  int uh = v & 1; int rv = v >> 1;       // rv in [0,768)
  int b = rv / 192, r = rv - b*192;

  int tid = threadIdx.x, lane = tid & 63;
  int p = tid >> 6;                      // wave = parity
  int n = lane & 15, s = lane >> 4;
  int u0w = uh*48;

  const u16* Brow = C2 + ((size_t)(b+4)*HW + (size_t)r*WW)*128;
  const u16* Aimg = C2 + (size_t)b*HW*128;

  // B-frags held in regs for the whole kernel: 5 z-tiles (u-half + halo).
  uint4 bf[4][5];
  #pragma unroll
  for (int l = 0; l < 5; ++l){
    int zq = u0w + 16*l + n - 16;
    bool vz = ((unsigned)zq < 96u);
    const u16* bp = Brow + (long)(2*zq + p)*128;
    #pragma unroll
    for (int kk = 0; kk < 4; ++kk){
      uint4 t0 = make_uint4(0,0,0,0);
      if (vz) t0 = *(const uint4*)(bp + (kk*4 + s)*8);
      bf[kk][l] = t0;
    }
  }

  int dylo = max(0, (r-170)>>1);
  int dyhi = min(20, (r+20)>>1);

  uint4 A[3][4];
  f32x4 acc[3][3];

  auto loadA = [&](int yy){
    const u16* Ay = Aimg + (size_t)yy*WW*128;
    #pragma unroll
    for (int t = 0; t < 3; ++t){
      const u16* apx = Ay + (size_t)(2*(u0w + 16*t + n) + p)*128;
      #pragma unroll
      for (int kk = 0; kk < 4; ++kk)
        A[t][kk] = *(const uint4*)(apx + (kk*4 + s)*8);
    }
  };

  int nm6 = n - 4*s - 6;
  auto eout = [&](int yy, int dyy){
    // band extract: d = 16j + n - (4s+q) - 6; local x' = 32t + p + 8s + 2q
    #pragma unroll
    for (int t = 0; t < 3; ++t){
      int xb2 = 32*t + p + 8*s;
      #pragma unroll
      for (int j = 0; j < 3; ++j){
        #pragma unroll
        for (int q = 0; q < 4; ++q){
          int dd = nm6 - q + 16*j;
          if ((unsigned)dd <= 20u){
            float val = acc[t][j][q]*(1.f/128.f);
            val = fmaxf(val, 0.f) + 0.1f*fminf(val, 0.f);
            smE[dd*100 + xb2 + 2*q] = f2b(val);
          }
        }
      }
    }
    __syncthreads();
    u16* Xp = X + ((size_t)(b*473 + 32 + dyy*21))*HW + (size_t)yy*WW + uh*96;
    #pragma unroll
    for (int e0 = 0; e0 < 8; ++e0){
      int e = e0*128 + tid;
      if (e < 1008){
        int d = e/48, xw = e - d*48;
        *(unsigned int*)(Xp + (size_t)d*HW + 2*xw) = *(const unsigned int*)(smE + d*100 + 2*xw);
      }
    }
    __syncthreads();
  };

  loadA(r + 20 - 2*dylo);

  #pragma unroll 1
  for (int dy = dylo; dy <= dyhi; ++dy){
    int y = r + 20 - 2*dy;
    if (dy > dylo) eout(y + 2, dy - 1);
    #pragma unroll
    for (int t = 0; t < 3; ++t)
      #pragma unroll
      for (int j = 0; j < 3; ++j)
        acc[t][j] = (f32x4){0.f, 0.f, 0.f, 0.f};
    #pragma unroll
    for (int kk = 0; kk < 4; ++kk)
      #pragma unroll
      for (int t = 0; t < 3; ++t)
        #pragma unroll
        for (int j = 0; j < 3; ++j)
          acc[t][j] = __builtin_amdgcn_mfma_f32_16x16x32_bf16(
              s8(A[t][kk]), s8(bf[kk][t+j]), acc[t][j], 0, 0, 0);
    if (dy < dyhi) loadA(y - 2);
  }
  eout(r + 20 - 2*dyhi, dyhi);
}

// Final 3x3 conv: contribution-passing, round 12: BRANCHLESS batched loads.
__global__ __launch_bounds__(192,2) void final_k(const u16* __restrict__ X, const unsigned int* __restrict__ wpb,
                                                 void* __restrict__ out, const int* __restrict__ flag){
  __shared__ float eR[4][2], eL[4][2];
  int x = threadIdx.x, y = blockIdx.x, b = blockIdx.y;
  int w = x >> 6, lane = x & 63;
  const u16* Xb = X + (size_t)b*473*HW;
  float Pm0=0.f,Pm1=0.f,Pl0=0.f,Pl1=0.f,Pr0=0.f,Pr1=0.f;
  bool rok0 = (y > 0), rok2 = (y < HH-1);
  size_t off0 = (size_t)(y-1)*WW + x;
  size_t off1 = (size_t)(y  )*WW + x;
  size_t off2 = (size_t)(y+1)*WW + x;

  #pragma unroll 1
  for (int it = 0; it < 59; ++it){
    int cp0 = it*4;
    unsigned int vv[4][3];
    #pragma unroll
    for (int u = 0; u < 4; ++u){
      size_t base0 = (size_t)(2*(cp0+u))*HW;
      size_t base1 = base0 + HW;
      #pragma unroll
      for (int r = 0; r < 3; ++r){
        size_t off = (r==0) ? off0 : ((r==2) ? off2 : off1);
        unsigned int lo = Xb[base0 + off];
        unsigned int hi = Xb[base1 + off];
        vv[u][r] = lo | (hi << 16);
      }
    }
    if (!rok0){ vv[0][0]=0u; vv[1][0]=0u; vv[2][0]=0u; vv[3][0]=0u; }
    if (!rok2){ vv[0][2]=0u; vv[1][2]=0u; vv[2][2]=0u; vv[3][2]=0u; }
    #pragma unroll
    for (int u = 0; u < 4; ++u){
      const unsigned int* w18 = wpb + (cp0+u)*18;
      #pragma unroll
      for (int r = 0; r < 3; ++r){
        unsigned int v = vv[u][r];
        Pm0 = dot2bf(v, w18[(r*3+1)*2+0], Pm0);
        Pm1 = dot2bf(v, w18[(r*3+1)*2+1], Pm1);
        Pl0 = dot2bf(v, w18[(r*3+2)*2+0], Pl0);
        Pl1 = dot2bf(v, w18[(r*3+2)*2+1], Pl1);
        Pr0 = dot2bf(v, w18[(r*3+0)*2+0], Pr0);
        Pr1 = dot2bf(v, w18[(r*3+0)*2+1], Pr1);
      }
    }
  }
  { // tail pair cp=236 (c0=472, c1 OOB -> weight hi already 0; load lo only)
    const unsigned int* w18 = wpb + 236*18;
    size_t base0 = (size_t)472*HW;
    unsigned int vv[3];
    vv[0] = Xb[base0 + off0];
    vv[1] = Xb[base0 + off1];
    vv[2] = Xb[base0 + off2];
    if (!rok0) vv[0] = 0u;
    if (!rok2) vv[2] = 0u;
    #pragma unroll
    for (int r = 0; r < 3; ++r){
      unsigned int v = vv[r];
      Pm0 = dot2bf(v, w18[(r*3+1)*2+0], Pm0);
      Pm1 = dot2bf(v, w18[(r*3+1)*2+1], Pm1);
      Pl0 = dot2bf(v, w18[(r*3+2)*2+0], Pl0);
      Pl1 = dot2bf(v, w18[(r*3+2)*2+1], Pl1);
      Pr0 = dot2bf(v, w18[(r*3+0)*2+0], Pr0);
      Pr1 = dot2bf(v, w18[(r*3+0)*2+1], Pr1);
    }
  }

  float r0 = __shfl_up(Pr0,1), r1 = __shfl_up(Pr1,1);
  float l0 = __shfl_down(Pl0,1), l1 = __shfl_down(Pl1,1);
  if (x == 0){ eR[0][0]=0.f; eR[0][1]=0.f; eL[3][0]=0.f; eL[3][1]=0.f; }
  if (lane == 63){ eR[w+1][0]=Pr0; eR[w+1][1]=Pr1; }
  if (lane == 0 && w > 0){ eL[w][0]=Pl0; eL[w][1]=Pl1; }
  __syncthreads();
  if (lane == 0){ r0 = eR[w][0]; r1 = eR[w][1]; }
  if (lane == 63){ l0 = eL[w+1][0]; l1 = eL[w+1][1]; }
  float a0 = Pm0 + r0 + l0;
  float a1 = Pm1 + r1 + l1;

  size_t rem = (size_t)y*WW + x;
  size_t i0 = (size_t)(b*2)*HW + rem;
  size_t i1 = (size_t)(b*2+1)*HW + rem;
  if (*flag){
    ((u16*)out)[i0] = f2b(a0);
    ((u16*)out)[i1] = f2b(a1);
  } else {
    ((float*)out)[i0] = a0;
    ((float*)out)[i1] = a1;
  }
}

// Workspace (bytes):
//   C2 [0, 75497472)           conv2 out NHWC bf16 [8][HW][128]
//   X1 [75497472, 113246208)   cvt out NHWC bf16 [8][HW][64] (dies after conv1)
//   H1 [113246208, 150994944)  conv1 out NHWC bf16 (dies after conv2)
//   X  [75497472, 214958080)   concat NCHW bf16 [4][473][HW] (overlays X1+H1)
//   weights at 215322624 (~260 KB)
extern "C" void kernel_launch(void* const* d_in, const int* in_sizes, int n_in,
                              void* d_out, int out_size, void* d_ws, size_t ws_size,
                              hipStream_t stream){
  char* ws = (char*)d_ws;
  u16* C2 = (u16*)ws;
  u16* X1 = (u16*)(ws + 75497472);
  u16* H1 = (u16*)(ws + 113246208);
  u16* X  = (u16*)(ws + 75497472);
  u16* w1m = (u16*)(ws + 215322624);
  u16* w2m = w1m + 36864;
  float* wrf = (float*)(w2m + 73728);
  unsigned int* wpb = (unsigned int*)(wrf + 4096);
  float* b1f = (float*)(wpb + 4266);
  float* b2f = b1f + 64;
  float* rbf = b2f + 128;
  int* flag  = (int*)(rbf + 32);

  detect_k<<<1,256,0,stream>>>((const unsigned int*)d_in[0], flag);
  cvt_t<<<dim3(576,8),256,0,stream>>>(d_in[0], d_in[1], X1, flag);
  prep_w<<<288,256,0,stream>>>(d_in[2], d_in[4], d_in[6], d_in[8],
                               d_in[3], d_in[5], d_in[7],
                               w1m, w2m, wrf, wpb, b1f, b2f, rbf, flag);
  conv_mfma<1><<<dim3(6,48,8),128,0,stream>>>(X1, w1m, b1f, H1);
  conv_mfma<2><<<dim3(6,48,8),256,0,stream>>>(H1, w2m, b2f, C2);
  redir_k<<<576,256,0,stream>>>(C2, wrf, rbf, X);
  zero_k<<<dim3(40,4),256,0,stream>>>(X);
  corr_k<<<dim3(1536),128,0,stream>>>(C2, X);
  final_k<<<dim3(192,4),192,0,stream>>>(X, wpb, d_out, flag);
}

// Round 8
// 508.633 us; speedup vs baseline: 1.2584x; 1.2584x over previous
//
#include <hip/hip_runtime.h>
#include <hip/hip_bf16.h>

#define HH 192
#define WW 192
#define HW (HH*WW)

typedef unsigned short u16;
typedef __attribute__((ext_vector_type(8))) short short8;
typedef __attribute__((ext_vector_type(16))) float float16;
typedef __attribute__((ext_vector_type(4))) float f32x4;

__device__ __forceinline__ float b2f(u16 u){
  union { unsigned int i; float f; } v; v.i = ((unsigned int)u) << 16; return v.f;
}
__device__ __forceinline__ u16 f2b(float f){
  union { unsigned int i; float f; } v; v.f = f;
  unsigned int r = v.i + 0x7FFFu + ((v.i >> 16) & 1u);
  return (u16)(r >> 16);
}
__device__ __forceinline__ void up2(unsigned int w, float& lo, float& hi){
  union { unsigned int i; float f; } a, b;
  a.i = w << 16; b.i = w & 0xFFFF0000u;
  lo = a.f; hi = b.f;
}
__device__ __forceinline__ float lrelu(float x){ return x >= 0.f ? x : 0.1f*x; }
__device__ __forceinline__ float ldmix(const void* p, int i, bool bf){
  return bf ? b2f(((const u16*)p)[i]) : ((const float*)p)[i];
}

using bf2 = __attribute__((ext_vector_type(2))) __bf16;
__device__ __forceinline__ float dot2bf(unsigned int a, unsigned int b, float c){
#if __has_builtin(__builtin_amdgcn_fdot2_f32_bf16)
  union { unsigned int u; bf2 v; } ua, ub; ua.u = a; ub.u = b;
  return __builtin_amdgcn_fdot2_f32_bf16(ua.v, ub.v, c, false);
#else
  float al,ah,bl,bh; up2(a,al,ah); up2(b,bl,bh);
  return c + al*bl + ah*bh;
#endif
}

union AU { uint4 q; short8 s; };
__device__ __forceinline__ short8 s8(const uint4& q){ AU u; u.q = q; return u.s; }

__global__ __launch_bounds__(256) void detect_k(const unsigned int* __restrict__ w, int* __restrict__ flag){
  __shared__ int cnt;
  if (threadIdx.x == 0) cnt = 0;
  __syncthreads();
  unsigned int v = w[(size_t)threadIdx.x * 1024];
  int e = (v >> 7) & 0xFF;
  bool ok = ((v & 0xFFFFu) == 0u) || (e > 100 && e < 150);
  if (ok) atomicAdd(&cnt, 1);
  __syncthreads();
  if (threadIdx.x == 0) *flag = (cnt >= 192) ? 1 : 0;
}

// NCHW (fp32 or bf16) -> NHWC bf16 [8][HW][64] via LDS transpose tile.
__global__ __launch_bounds__(256) void cvt_t(const void* __restrict__ pred, const void* __restrict__ refp,
                                             u16* __restrict__ X1, const int* __restrict__ flag){
  __shared__ u16 t[64*72];
  int tid = threadIdx.x;
  int px0 = blockIdx.x*64, img = blockIdx.y;
  bool bf = (*flag != 0);
  const void* src = (img < 4) ? pred : refp;
  int im = (img < 4) ? img : img - 4;
  for (int e = tid; e < 4096; e += 256){
    int ch = e >> 6, px = e & 63;
    t[px*72 + ch] = f2b(ldmix(src, (im*64 + ch)*HW + px0 + px, bf));
  }
  __syncthreads();
  int px = tid >> 2, q = tid & 3;
  uint4 v0 = *(const uint4*)(t + px*72 + q*16);
  uint4 v1 = *(const uint4*)(t + px*72 + q*16 + 8);
  u16* dst = X1 + ((size_t)img*HW + px0 + px)*64 + q*16;
  *(uint4*)dst = v0;
  *(uint4*)(dst + 8) = v1;
}

// Weight prep.
__global__ __launch_bounds__(256) void prep_w(const void* __restrict__ w1, const void* __restrict__ w2,
                                              const void* __restrict__ wr, const void* __restrict__ wp,
                                              const void* __restrict__ b1, const void* __restrict__ b2,
                                              const void* __restrict__ rb,
                                              u16* __restrict__ w1m, u16* __restrict__ w2m,
                                              float* __restrict__ wrf, unsigned int* __restrict__ wpb,
                                              float* __restrict__ b1f, float* __restrict__ b2f,
                                              float* __restrict__ rbf, const int* __restrict__ flag){
  int i = blockIdx.x*256 + threadIdx.x;
  bool bf = (*flag != 0);
  if (i < 36864){
    int j = i & 7, lane = (i>>3) & 63, cot = (i>>9) & 1, ks = (i>>10) & 3, tap = i >> 12;
    int co = cot*32 + (lane & 31), ci = ks*16 + (lane>>5)*8 + j;
    w1m[i] = f2b(ldmix(w1, (co*64 + ci)*9 + tap, bf));
  }
  if (i < 73728){
    int j = i & 7, lane = (i>>3) & 63, cot = (i>>9) & 3, ks = (i>>11) & 3, tap = i >> 13;
    int co = cot*32 + (lane & 31), ci = ks*16 + (lane>>5)*8 + j;
    w2m[i] = f2b(ldmix(w2, (co*64 + ci)*9 + tap, bf));
  }
  if (i < 4096){ int co = i & 31; int ci = i >> 5;
    wrf[ci*32+co] = ldmix(wr, co*128+ci, bf); }
  if (i < 4266){
    int cp = i/18; int rr = i - cp*18; int tap = rr >> 1; int o = rr & 1;
    int c0 = 2*cp, c1 = c0 + 1;
    float f0 = ldmix(wp, (o*473+c0)*9+tap, bf);
    float f1 = (c1 < 473) ? ldmix(wp, (o*473+c1)*9+tap, bf) : 0.f;
    wpb[i] = (unsigned int)f2b(f0) | ((unsigned int)f2b(f1) << 16);
  }
  if (i < 64)  b1f[i] = ldmix(b1, i, bf);
  if (i < 128) b2f[i] = ldmix(b2, i, bf);
  if (i < 32)  rbf[i] = ldmix(rb, i, bf);
}

// MFMA implicit-GEMM 3x3 conv, pad=1, NHWC bf16 in/out, bias+lrelu.
template<int WCO>
__global__ __launch_bounds__(WCO*128) void conv_mfma(const u16* __restrict__ in, const u16* __restrict__ wm,
                                                     const float* __restrict__ bias, u16* __restrict__ out){
  constexpr int COUT = WCO*64;
  constexpr int NCOT = WCO*2;
  constexpr int THREADS = WCO*128;
  constexpr int CO_PAD = COUT + 8;
  constexpr int SLAB = 6*34*72;            // 14688 u16
  constexpr int OT   = 128*CO_PAD;
  __shared__ __align__(16) u16 smem[(SLAB > OT) ? SLAB : OT];

  int tid = threadIdx.x, lane = tid & 63, w = tid >> 6;
  int wr = w & 1, wc = w >> 1;
  int n = lane & 31, kh = lane >> 5;
  int x0 = blockIdx.x*32, y0 = blockIdx.y*4, img = blockIdx.z;
  const u16* inb = in + (size_t)img*HW*64;

  float16 acc[2][2];
  #pragma unroll
  for (int t=0;t<2;t++)
    #pragma unroll
    for (int c=0;c<2;c++)
      #pragma unroll
      for (int k=0;k<16;k++) acc[t][c][k] = 0.f;

  for (int e = tid; e < 1632; e += THREADS){
    int c8 = e & 7; int pp = e >> 3;
    int row = pp / 34, pos = pp - row*34;
    int gy = y0 + row - 1, gx = x0 + pos - 1;
    uint4 v = make_uint4(0,0,0,0);
    if (gy >= 0 && gy < HH && gx >= 0 && gx < WW)
      v = *(const uint4*)(inb + ((size_t)gy*WW + gx)*64 + c8*8);
    *(uint4*)(smem + pp*72 + c8*8) = v;
  }
  __syncthreads();

  union BU { uint2 u[2]; short8 s; };

  #pragma unroll 1
  for (int ky = 0; ky < 3; ++ky){
    #pragma unroll 1
    for (int kx = 0; kx < 3; ++kx){
      int tap = ky*3 + kx;
      #pragma unroll
      for (int ks = 0; ks < 4; ++ks){
        AU a0, a1;
        const u16* wmp = wm + (((size_t)(tap*4 + ks)*NCOT + wc*2)*64 + lane)*8;
        a0.q = *(const uint4*)(wmp);
        a1.q = *(const uint4*)(wmp + 512);
        #pragma unroll
        for (int t = 0; t < 2; ++t){
          int row = wr*2 + t + ky;
          int off = (row*34 + n + kx)*72 + ks*16 + kh*8;
          BU b;
          b.u[0] = *(const uint2*)(smem + off);
          b.u[1] = *(const uint2*)(smem + off + 4);
          acc[t][0] = __builtin_amdgcn_mfma_f32_32x32x16_bf16(a0.s, b.s, acc[t][0], 0, 0, 0);
          acc[t][1] = __builtin_amdgcn_mfma_f32_32x32x16_bf16(a1.s, b.s, acc[t][1], 0, 0, 0);
        }
      }
    }
  }

  __syncthreads();
  #pragma unroll
  for (int t = 0; t < 2; ++t){
    int pxl = (wr*2 + t)*32 + n;
    #pragma unroll
    for (int c = 0; c < 2; ++c){
      int cob = wc*64 + c*32 + 4*kh;
      #pragma unroll
      for (int p = 0; p < 8; ++p){
        int co = cob + (p&1)*2 + (p>>1)*8;
        float2 bb = *(const float2*)(bias + co);
        float v0 = lrelu(acc[t][c][2*p]   + bb.x);
        float v1 = lrelu(acc[t][c][2*p+1] + bb.y);
        unsigned int pk = (unsigned int)f2b(v0) | ((unsigned int)f2b(v1) << 16);
        *(unsigned int*)(smem + pxl*CO_PAD + co) = pk;
      }
    }
  }
  __syncthreads();
  int px, part;
  if (WCO == 2){ px = tid >> 1; part = tid & 1; } else { px = tid; part = 0; }
  const u16* sp = smem + px*CO_PAD + part*64;
  u16* gp = out + ((size_t)img*HW + (size_t)(y0 + (px>>5))*WW + x0 + (px&31))*COUT + part*64;
  #pragma unroll
  for (int k = 0; k < 8; ++k)
    *(uint4*)(gp + k*8) = *(const uint4*)(sp + k*8);
}

// 1x1 redir conv (128->32) + bias + lrelu. X NCHW [b][473][HW]; planes 0..31.
__global__ __launch_bounds__(256) void redir_k(const u16* __restrict__ C2, const float* __restrict__ wrf,
                                               const float* __restrict__ rbf, u16* __restrict__ X){
  int p = blockIdx.x*256 + threadIdx.x;
  int b = p / HW; int pix = p - b*HW;
  const u16* ap = C2 + (size_t)p*128;
  float acc[32];
  #pragma unroll
  for (int j=0;j<32;j++) acc[j]=0.f;
  for (int ci=0; ci<128; ci+=4){
    uint2 aw = *(const uint2*)(ap + ci);
    float a0,a1,a2,a3;
    up2(aw.x,a0,a1); up2(aw.y,a2,a3);
    const float* w0 = wrf + ci*32;
    #pragma unroll
    for (int co=0; co<32; co+=4){
      float4 wv0 = *(const float4*)(w0+co);
      float4 wv1 = *(const float4*)(w0+32+co);
      float4 wv2 = *(const float4*)(w0+64+co);
      float4 wv3 = *(const float4*)(w0+96+co);
      acc[co+0] += a0*wv0.x + a1*wv1.x + a2*wv2.x + a3*wv3.x;
      acc[co+1] += a0*wv0.y + a1*wv1.y + a2*wv2.y + a3*wv3.y;
      acc[co+2] += a0*wv0.z + a1*wv1.z + a2*wv2.z + a3*wv3.z;
      acc[co+3] += a0*wv0.w + a1*wv1.w + a2*wv2.w + a3*wv3.w;
    }
  }
  #pragma unroll
  for (int co=0; co<32; ++co){
    X[(size_t)(b*473 + co)*HW + pix] = f2b(lrelu(acc[co] + rbf[co]));
  }
}

// Zero the orphan (y,dy) plane rows (r = y+2dy-20 outside [0,192)).
__global__ __launch_bounds__(256) void zero_k(u16* __restrict__ X){
  int yi = blockIdx.x, b = blockIdx.y;
  int y = (yi < 20) ? yi : 152 + yi;           // y in [0,20) or [172,192)
  int locnt = (yi < 20) ? ((21 - y) >> 1) : 0; // orphan dy = 0..locnt-1
  int hi0 = (213 - y) >> 1;                    // first orphan dy at high end
  int hicnt = (yi < 20) ? 0 : (21 - hi0);
  int ncnt = locnt + hicnt;
  u16* Xb = X + ((size_t)(b*473 + 32))*HW + (size_t)y*WW;
  int total = ncnt*2016;
  for (int e = threadIdx.x; e < total; e += 256){
    int i = e / 2016, rem = e - i*2016;
    int dy = (i < locnt) ? i : (hi0 + i - locnt);
    int d = rem / 96, xw = rem - d*96;
    *(unsigned int*)(Xb + ((size_t)(dy*21 + d))*HW + 2*xw) = 0u;
  }
}

// ---------------------------------------------------------------------------
// Correlation, round 14: round-10 structure (4-wave, 256 thr, VGPR-resident
// B-frags, no spill) + two orthogonal fixes for the barrier/residency stall:
//  (a) dy-range of each (b,r) split across 2 blocks (contiguous halves):
//      1536 blocks -> 6/CU grid supply, 4/CU VGPR-resident; per-block work
//      halves so tail imbalance halves. B-frags read twice (L2-hot, same
//      XCD via swizzle pairing).
//  (b) ONE barrier per dy via double-buffered smE: compute(dy) ->
//      store(dy-1, buf (dy-1)&1) -> extract(dy, buf dy&1) -> sync.
//      Buffer overwrite (dy vs dy-2) is separated by the dy-1 sync.
// Round-13's failure (launch_bounds(128,3) -> VGPR cap 85 -> spill, FETCH
// 686MB) is avoided: launch_bounds(256,2) keeps cap 256, VGPR ~128.
// ---------------------------------------------------------------------------
__global__ __launch_bounds__(256,2) void corr_k(const u16* __restrict__ C2, u16* __restrict__ X){
  __shared__ __align__(16) u16 smE[2][4160];

  int bid = blockIdx.x;
  int v = (bid & 7)*192 + (bid >> 3);    // XCD-contiguous, bijective (1536 = 8*192)
  int h = v & 1; int rv = v >> 1;
  int b = rv / 192, r = rv - b*192;

  int tid = threadIdx.x, lane = tid & 63, w = tid >> 6;
  int n = lane & 15, s = lane >> 4;
  int p = w & 1, u0w = (w >> 1)*48;

  int dylo0 = max(0, (r-170)>>1);
  int dyhi0 = min(20, (r+20)>>1);
  int dmid = (dylo0 + dyhi0) >> 1;
  int dylo = h ? (dmid + 1) : dylo0;
  int dyhi = h ? dyhi0 : dmid;

  const u16* Brow = C2 + ((size_t)(b+4)*HW + (size_t)r*WW)*128;
  const u16* Aimg = C2 + (size_t)b*HW*128;

  uint4 bf[4][5];
  #pragma unroll
  for (int l = 0; l < 5; ++l){
    int zq = u0w + 16*l + n - 16;
    bool vz = ((unsigned)zq < 96u);
    const u16* bp = Brow + (long)(2*zq + p)*128;
    #pragma unroll
    for (int kk = 0; kk < 4; ++kk){
      uint4 t0 = make_uint4(0,0,0,0);
      if (vz) t0 = *(const uint4*)(bp + (kk*4 + s)*8);
      bf[kk][l] = t0;
    }
  }

  uint4 A[3][4];
  f32x4 acc[3][3];

  auto loadA = [&](int yy){
    const u16* Ay = Aimg + (size_t)yy*WW*128;
    #pragma unroll
    for (int t = 0; t < 3; ++t){
      const u16* apx = Ay + (size_t)(2*(u0w + 16*t + n) + p)*128;
      #pragma unroll
      for (int kk = 0; kk < 4; ++kk)
        A[t][kk] = *(const uint4*)(apx + (kk*4 + s)*8);
    }
  };

  int nm6 = n - 4*s - 6;
  auto extract = [&](int dyy){
    u16* E = smE[dyy & 1];
    #pragma unroll
    for (int t = 0; t < 3; ++t){
      int xb2 = 2*(u0w + 16*t) + p + 8*s;
      #pragma unroll
      for (int j = 0; j < 3; ++j){
        #pragma unroll
        for (int q = 0; q < 4; ++q){
          int dd = nm6 - q + 16*j;
          if ((unsigned)dd <= 20u){
            float val = acc[t][j][q]*(1.f/128.f);
            val = fmaxf(val, 0.f) + 0.1f*fminf(val, 0.f);
            E[dd*198 + xb2 + 2*q] = f2b(val);
          }
        }
      }
    }
  };
  auto store = [&](int yy, int dyy){
    const u16* E = smE[dyy & 1];
    u16* Xp = X + ((size_t)(b*473 + 32 + dyy*21))*HW + (size_t)yy*WW;
    #pragma unroll
    for (int e0 = 0; e0 < 8; ++e0){
      int e = e0*256 + tid;
      if (e < 2016){
        int d = e/96, xw = e - d*96;
        *(unsigned int*)(Xp + (size_t)d*HW + 2*xw) = *(const unsigned int*)(E + d*198 + 2*xw);
      }
    }
  };

  loadA(r + 20 - 2*dylo);

  #pragma unroll 1
  for (int dy = dylo; dy <= dyhi; ++dy){
    int y = r + 20 - 2*dy;
    #pragma unroll
    for (int t = 0; t < 3; ++t)
      #pragma unroll
      for (int j = 0; j < 3; ++j)
        acc[t][j] = (f32x4){0.f, 0.f, 0.f, 0.f};
    #pragma unroll
    for (int kk = 0; kk < 4; ++kk)
      #pragma unroll
      for (int t = 0; t < 3; ++t)
        #pragma unroll
        for (int j = 0; j < 3; ++j)
          acc[t][j] = __builtin_amdgcn_mfma_f32_16x16x32_bf16(
              s8(A[t][kk]), s8(bf[kk][t+j]), acc[t][j], 0, 0, 0);
    if (dy < dyhi) loadA(y - 2);
    if (dy > dylo) store(y + 2, dy - 1);
    extract(dy);
    __syncthreads();
  }
  store(r + 20 - 2*dyhi, dyhi);
}

// Final 3x3 conv: contribution-passing, round 12: BRANCHLESS batched loads.
__global__ __launch_bounds__(192,2) void final_k(const u16* __restrict__ X, const unsigned int* __restrict__ wpb,
                                                 void* __restrict__ out, const int* __restrict__ flag){
  __shared__ float eR[4][2], eL[4][2];
  int x = threadIdx.x, y = blockIdx.x, b = blockIdx.y;
  int w = x >> 6, lane = x & 63;
  const u16* Xb = X + (size_t)b*473*HW;
  float Pm0=0.f,Pm1=0.f,Pl0=0.f,Pl1=0.f,Pr0=0.f,Pr1=0.f;
  bool rok0 = (y > 0), rok2 = (y < HH-1);
  size_t off0 = (size_t)(y-1)*WW + x;
  size_t off1 = (size_t)(y  )*WW + x;
  size_t off2 = (size_t)(y+1)*WW + x;

  #pragma unroll 1
  for (int it = 0; it < 59; ++it){
    int cp0 = it*4;
    unsigned int vv[4][3];
    #pragma unroll
    for (int u = 0; u < 4; ++u){
      size_t base0 = (size_t)(2*(cp0+u))*HW;
      size_t base1 = base0 + HW;
      #pragma unroll
      for (int r = 0; r < 3; ++r){
        size_t off = (r==0) ? off0 : ((r==2) ? off2 : off1);
        unsigned int lo = Xb[base0 + off];
        unsigned int hi = Xb[base1 + off];
        vv[u][r] = lo | (hi << 16);
      }
    }
    if (!rok0){ vv[0][0]=0u; vv[1][0]=0u; vv[2][0]=0u; vv[3][0]=0u; }
    if (!rok2){ vv[0][2]=0u; vv[1][2]=0u; vv[2][2]=0u; vv[3][2]=0u; }
    #pragma unroll
    for (int u = 0; u < 4; ++u){
      const unsigned int* w18 = wpb + (cp0+u)*18;
      #pragma unroll
      for (int r = 0; r < 3; ++r){
        unsigned int v = vv[u][r];
        Pm0 = dot2bf(v, w18[(r*3+1)*2+0], Pm0);
        Pm1 = dot2bf(v, w18[(r*3+1)*2+1], Pm1);
        Pl0 = dot2bf(v, w18[(r*3+2)*2+0], Pl0);
        Pl1 = dot2bf(v, w18[(r*3+2)*2+1], Pl1);
        Pr0 = dot2bf(v, w18[(r*3+0)*2+0], Pr0);
        Pr1 = dot2bf(v, w18[(r*3+0)*2+1], Pr1);
      }
    }
  }
  { // tail pair cp=236 (c0=472, c1 OOB -> weight hi already 0; load lo only)
    const unsigned int* w18 = wpb + 236*18;
    size_t base0 = (size_t)472*HW;
    unsigned int vv[3];
    vv[0] = Xb[base0 + off0];
    vv[1] = Xb[base0 + off1];
    vv[2] = Xb[base0 + off2];
    if (!rok0) vv[0] = 0u;
    if (!rok2) vv[2] = 0u;
    #pragma unroll
    for (int r = 0; r < 3; ++r){
      unsigned int v = vv[r];
      Pm0 = dot2bf(v, w18[(r*3+1)*2+0], Pm0);
      Pm1 = dot2bf(v, w18[(r*3+1)*2+1], Pm1);
      Pl0 = dot2bf(v, w18[(r*3+2)*2+0], Pl0);
      Pl1 = dot2bf(v, w18[(r*3+2)*2+1], Pl1);
      Pr0 = dot2bf(v, w18[(r*3+0)*2+0], Pr0);
      Pr1 = dot2bf(v, w18[(r*3+0)*2+1], Pr1);
    }
  }

  float r0 = __shfl_up(Pr0,1), r1 = __shfl_up(Pr1,1);
  float l0 = __shfl_down(Pl0,1), l1 = __shfl_down(Pl1,1);
  if (x == 0){ eR[0][0]=0.f; eR[0][1]=0.f; eL[3][0]=0.f; eL[3][1]=0.f; }
  if (lane == 63){ eR[w+1][0]=Pr0; eR[w+1][1]=Pr1; }
  if (lane == 0 && w > 0){ eL[w][0]=Pl0; eL[w][1]=Pl1; }
  __syncthreads();
  if (lane == 0){ r0 = eR[w][0]; r1 = eR[w][1]; }
  if (lane == 63){ l0 = eL[w+1][0]; l1 = eL[w+1][1]; }
  float a0 = Pm0 + r0 + l0;
  float a1 = Pm1 + r1 + l1;

  size_t rem = (size_t)y*WW + x;
  size_t i0 = (size_t)(b*2)*HW + rem;
  size_t i1 = (size_t)(b*2+1)*HW + rem;
  if (*flag){
    ((u16*)out)[i0] = f2b(a0);
    ((u16*)out)[i1] = f2b(a1);
  } else {
    ((float*)out)[i0] = a0;
    ((float*)out)[i1] = a1;
  }
}

// Workspace (bytes):
//   C2 [0, 75497472)           conv2 out NHWC bf16 [8][HW][128]
//   X1 [75497472, 113246208)   cvt out NHWC bf16 [8][HW][64] (dies after conv1)
//   H1 [113246208, 150994944)  conv1 out NHWC bf16 (dies after conv2)
//   X  [75497472, 214958080)   concat NCHW bf16 [4][473][HW] (overlays X1+H1)
//   weights at 215322624 (~260 KB)
extern "C" void kernel_launch(void* const* d_in, const int* in_sizes, int n_in,
                              void* d_out, int out_size, void* d_ws, size_t ws_size,
                              hipStream_t stream){
  char* ws = (char*)d_ws;
  u16* C2 = (u16*)ws;
  u16* X1 = (u16*)(ws + 75497472);
  u16* H1 = (u16*)(ws + 113246208);
  u16* X  = (u16*)(ws + 75497472);
  u16* w1m = (u16*)(ws + 215322624);
  u16* w2m = w1m + 36864;
  float* wrf = (float*)(w2m + 73728);
  unsigned int* wpb = (unsigned int*)(wrf + 4096);
  float* b1f = (float*)(wpb + 4266);
  float* b2f = b1f + 64;
  float* rbf = b2f + 128;
  int* flag  = (int*)(rbf + 32);

  detect_k<<<1,256,0,stream>>>((const unsigned int*)d_in[0], flag);
  cvt_t<<<dim3(576,8),256,0,stream>>>(d_in[0], d_in[1], X1, flag);
  prep_w<<<288,256,0,stream>>>(d_in[2], d_in[4], d_in[6], d_in[8],
                               d_in[3], d_in[5], d_in[7],
                               w1m, w2m, wrf, wpb, b1f, b2f, rbf, flag);
  conv_mfma<1><<<dim3(6,48,8),128,0,stream>>>(X1, w1m, b1f, H1);
  conv_mfma<2><<<dim3(6,48,8),256,0,stream>>>(H1, w2m, b2f, C2);
  redir_k<<<576,256,0,stream>>>(C2, wrf, rbf, X);
  zero_k<<<dim3(40,4),256,0,stream>>>(X);
  corr_k<<<dim3(1536),256,0,stream>>>(C2, X);
  final_k<<<dim3(192,4),192,0,stream>>>(X, wpb, d_out, flag);
}